// Round 1
// baseline (255.127 us; speedup 1.0000x reference)
//
#include <hip/hip_runtime.h>
#include <math.h>

// Capsule routing, fully fused. Shapes fixed by the problem:
#define BB 64      // batch
#define II 1024    // in caps
#define OO 1024    // out caps
#define EPSF 1e-5f

// Stage kernel mapping: one wave owns one (b,i) softmax row of 1024 o's.
// lane L holds o = j*256 + L*4 + e  (j=0..3, e=0..3) -> all loads coalesced
// float4, all reductions are 6-step shuffles, zero LDS, zero barriers.
#define IBLKS 16   // i-chunks per b  -> grid = 64*16 = 1024 blocks
#define IW    16   // i's per wave    -> 16 (chunks) * 4 (waves) * 16 = 1024 = II

__device__ __forceinline__ float wave_max(float v) {
    #pragma unroll
    for (int off = 32; off > 0; off >>= 1)
        v = fmaxf(v, __shfl_xor(v, off, 64));
    return v;
}
__device__ __forceinline__ float wave_sum(float v) {
    #pragma unroll
    for (int off = 32; off > 0; off >>= 1)
        v += __shfl_xor(v, off, 64);
    return v;
}

// acc[b,o] += sum_i u[b,i]*w[i,o]   (partial-dot with register acc + atomics)
__global__ __launch_bounds__(256) void gemm_partial(
    const float* __restrict__ u, const float* __restrict__ w,
    float* __restrict__ acc)
{
    const int b    = blockIdx.x >> 4;
    const int iblk = blockIdx.x & 15;
    const int wave = threadIdx.x >> 6;
    const int lane = threadIdx.x & 63;
    const float4* w4 = (const float4*)w;

    float a[16];
    #pragma unroll
    for (int k = 0; k < 16; k++) a[k] = 0.f;

    const int i0 = iblk * 64 + wave * IW;
    #pragma unroll 4
    for (int ii = 0; ii < IW; ii++) {
        const int i = i0 + ii;
        const float ub = u[b * II + i];          // wave-uniform -> s_load
        #pragma unroll
        for (int j = 0; j < 4; j++) {
            float4 wr = w4[i * 256 + j * 64 + lane];
            a[j*4+0] = fmaf(ub, wr.x, a[j*4+0]);
            a[j*4+1] = fmaf(ub, wr.y, a[j*4+1]);
            a[j*4+2] = fmaf(ub, wr.z, a[j*4+2]);
            a[j*4+3] = fmaf(ub, wr.w, a[j*4+3]);
        }
    }
    #pragma unroll
    for (int j = 0; j < 4; j++)
        #pragma unroll
        for (int e = 0; e < 4; e++)
            atomicAdd(&acc[b * OO + j * 256 + lane * 4 + e], a[j*4+e]);
}

// acc[b,o] += sum_i u*w*softmax_o(u[b,i]*w[i,o]*v[b,o])
__global__ __launch_bounds__(256) void stage_k(
    const float* __restrict__ u, const float* __restrict__ w,
    const float* __restrict__ v, float* __restrict__ acc)
{
    const int b    = blockIdx.x >> 4;
    const int iblk = blockIdx.x & 15;
    const int wave = threadIdx.x >> 6;
    const int lane = threadIdx.x & 63;
    const float4* w4 = (const float4*)w;
    const float4* v4 = (const float4*)(v + b * OO);

    float vv[16];
    #pragma unroll
    for (int j = 0; j < 4; j++) {
        float4 t = v4[j * 64 + lane];
        vv[j*4+0] = t.x; vv[j*4+1] = t.y; vv[j*4+2] = t.z; vv[j*4+3] = t.w;
    }

    float ar[16];
    #pragma unroll
    for (int k = 0; k < 16; k++) ar[k] = 0.f;

    const int i0 = iblk * 64 + wave * IW;
    #pragma unroll 2
    for (int ii = 0; ii < IW; ii++) {
        const int i = i0 + ii;
        const float ub = u[b * II + i];          // wave-uniform
        float uw[16], p[16];
        #pragma unroll
        for (int j = 0; j < 4; j++) {
            float4 wr = w4[i * 256 + j * 64 + lane];
            uw[j*4+0] = ub * wr.x; uw[j*4+1] = ub * wr.y;
            uw[j*4+2] = ub * wr.z; uw[j*4+3] = ub * wr.w;
        }
        float m = -3.4e38f;
        #pragma unroll
        for (int k = 0; k < 16; k++) {
            float t = uw[k] * vv[k];
            p[k] = t;
            m = fmaxf(m, t);
        }
        m = wave_max(m);
        float s = 0.f;
        #pragma unroll
        for (int k = 0; k < 16; k++) {
            p[k] = __expf(p[k] - m);
            s += p[k];
        }
        s = wave_sum(s);
        const float r = 1.0f / s;
        #pragma unroll
        for (int k = 0; k < 16; k++)
            ar[k] = fmaf(uw[k], p[k] * r, ar[k]);
    }
    #pragma unroll
    for (int j = 0; j < 4; j++)
        #pragma unroll
        for (int e = 0; e < 4; e++)
            atomicAdd(&acc[b * OO + j * 256 + lane * 4 + e], ar[j*4+e]);
}

// x = acc*scale + bias (row b); f = n2/((1+n2)(n+eps)); out per mode:
// mode 0: vbuf = x*f      mode 1: vbuf += x*f      mode 2: out = x*f
__global__ __launch_bounds__(256) void squash_k(
    const float* __restrict__ acc, const float* __restrict__ bias,
    float* __restrict__ vbuf, float* __restrict__ out,
    float scale, int mode)
{
    const int b = blockIdx.x;
    const int t = threadIdx.x;          // 256 threads, 4 o's each
    const float4* a4 = (const float4*)(acc + b * OO);
    const float4* b4 = (const float4*)bias;

    float4 x = a4[t];
    float4 bb = b4[t];
    x.x = fmaf(x.x, scale, bb.x);
    x.y = fmaf(x.y, scale, bb.y);
    x.z = fmaf(x.z, scale, bb.z);
    x.w = fmaf(x.w, scale, bb.w);

    float ss = x.x*x.x + x.y*x.y + x.z*x.z + x.w*x.w;
    ss = wave_sum(ss);
    __shared__ float red[4];
    if ((t & 63) == 0) red[t >> 6] = ss;
    __syncthreads();
    ss = red[0] + red[1] + red[2] + red[3];

    const float n  = sqrtf(ss);
    const float n2 = n * n;
    const float f  = n2 / ((1.f + n2) * (n + EPSF));

    float4 vout;
    vout.x = x.x * f; vout.y = x.y * f; vout.z = x.z * f; vout.w = x.w * f;

    if (mode == 0) {
        ((float4*)(vbuf + b * OO))[t] = vout;
    } else if (mode == 1) {
        float4 pv = ((const float4*)(vbuf + b * OO))[t];
        pv.x += vout.x; pv.y += vout.y; pv.z += vout.z; pv.w += vout.w;
        ((float4*)(vbuf + b * OO))[t] = pv;
    } else {
        ((float4*)(out + b * OO))[t] = vout;
    }
}

extern "C" void kernel_launch(void* const* d_in, const int* in_sizes, int n_in,
                              void* d_out, int out_size, void* d_ws, size_t ws_size,
                              hipStream_t stream) {
    const float* u    = (const float*)d_in[0];   // [64,1024]
    const float* w    = (const float*)d_in[1];   // [1024,1024]
    const float* bias = (const float*)d_in[2];   // [1024]
    float* out  = (float*)d_out;                 // [64,1024]
    float* acc  = (float*)d_ws;                  // 64K f32 accumulator
    float* vbuf = acc + BB * OO;                 // 64K f32 v / vsum
    const size_t accB = (size_t)BB * OO * sizeof(float);

    // s1 = (u@w)/O + bias ; v1 = squash(s1)
    hipMemsetAsync(acc, 0, accB, stream);
    gemm_partial<<<dim3(BB * IBLKS), dim3(256), 0, stream>>>(u, w, acc);
    squash_k<<<dim3(BB), dim3(256), 0, stream>>>(acc, bias, vbuf, out,
                                                 1.0f / (float)OO, 0);
    // stage A: s2 via softmax(u*w*v1) ; vsum = v1 + squash(s2+bias)
    hipMemsetAsync(acc, 0, accB, stream);
    stage_k<<<dim3(BB * IBLKS), dim3(256), 0, stream>>>(u, w, vbuf, acc);
    squash_k<<<dim3(BB), dim3(256), 0, stream>>>(acc, bias, vbuf, out, 1.0f, 1);
    // stage B: s3 via softmax(u*w*vsum) ; out = squash(s3+bias)
    hipMemsetAsync(acc, 0, accB, stream);
    stage_k<<<dim3(BB * IBLKS), dim3(256), 0, stream>>>(u, w, vbuf, acc);
    squash_k<<<dim3(BB), dim3(256), 0, stream>>>(acc, bias, vbuf, out, 1.0f, 2);
}